// Round 8
// baseline (474.745 us; speedup 1.0000x reference)
//
#include <hip/hip_runtime.h>

#define N_NODES 100000
#define N_EDGES 1600000
#define IN_C 165
#define HID_C 256
#define OUT_C 2

#define XPAD 168        // bf16 row length (16B-aligned: 21 uint4 / 42 uint2 chunks)
#define LDSROW 360      // LDS A-tile row stride in shorts
#define NBLK_SCAN 98    // ceil(100000/1024)
#define GNT 32          // nodes per gemm1 block (grid 3125 -> ~12 blocks/CU)

typedef short bf16x8 __attribute__((ext_vector_type(8)));
typedef float f32x4 __attribute__((ext_vector_type(4)));

__device__ inline unsigned short f2bf(float f) {
    unsigned int u = __float_as_uint(f);
    u += 0x7fffu + ((u >> 16) & 1u);
    return (unsigned short)(u >> 16);
}
__device__ inline float bf2f(unsigned short h) {
    return __uint_as_float(((unsigned int)h) << 16);
}
__device__ inline unsigned int pack2bf(float a, float b) {
    return (unsigned int)f2bf(a) | ((unsigned int)f2bf(b) << 16);
}

// ---------------------------------------------------------------------------
// Workspace layout (75.78 MB total — identical envelope to R4-R7, all passed):
//   csr    : ints  [0, 1600000)
//   rowptr : ints  [1600000, 1700001)
//   xb     : bf16  [N][168]   at int offset 1700004      (33.6 MB)
//   aggb   : bf16  [N][168]                              (33.6 MB)
//   Wt     : bf16  [256][352]                            (180 KB)
//   yz     : f32   [N][4]                                (1.6 MB)
// overlays on yz (all dead before k_gemm1 writes yz):
//   deg         : ints yz[0..100000)
//   incl/cursor : ints yz[100000..200000)
//   btot        : ints yz[200000..200098)
// ---------------------------------------------------------------------------

// XCD-partitioned degree histogram: role=blockIdx&7 owns dst range of 12500
// nodes; atomics on deg lines stay within one XCD's L2 (same fix as k_fill —
// R6 showed 16x dirty-line write amplification for cross-XCD scattered RMW).
__global__ void k_deg(const int* __restrict__ dst, int* __restrict__ deg) {
    const int role = blockIdx.x & 7;
    const int nchunk = gridDim.x >> 3;
    const int lo = role * (N_NODES / 8);
    const int hi = lo + (N_NODES / 8);
    for (int e = (blockIdx.x >> 3) * 256 + threadIdx.x; e < N_EDGES;
         e += nchunk * 256) {
        int d = dst[e];
        if (d >= lo && d < hi) atomicAdd(&deg[d], 1);
    }
}

// ---- parallel 3-pass scan ----
__launch_bounds__(1024)
__global__ void k_scan1(const int* __restrict__ deg, int* __restrict__ incl,
                        int* __restrict__ btot) {
    const int tid = threadIdx.x;
    const int idx = blockIdx.x * 1024 + tid;
    const int lane = tid & 63, wid = tid >> 6;
    __shared__ int ws[16];
    int v = (idx < N_NODES) ? deg[idx] : 0;
    int s = v;
#pragma unroll
    for (int off = 1; off < 64; off <<= 1) {
        int t = __shfl_up(s, off);
        if (lane >= off) s += t;
    }
    if (lane == 63) ws[wid] = s;
    __syncthreads();
    if (wid == 0) {
        int p = (lane < 16) ? ws[lane] : 0;
#pragma unroll
        for (int off = 1; off < 16; off <<= 1) {
            int t = __shfl_up(p, off);
            if (lane >= off) p += t;
        }
        if (lane < 16) ws[lane] = p;
    }
    __syncthreads();
    int blockincl = s + (wid > 0 ? ws[wid - 1] : 0);
    if (idx < N_NODES) incl[idx] = blockincl;
    if (tid == 1023) btot[blockIdx.x] = blockincl;   // block grand total
}

__global__ void k_scan2(int* __restrict__ btot) {   // 1 block, 64 threads
    const int lane = threadIdx.x;
    int a = (2 * lane < NBLK_SCAN) ? btot[2 * lane] : 0;
    int b = (2 * lane + 1 < NBLK_SCAN) ? btot[2 * lane + 1] : 0;
    int p = a + b;
#pragma unroll
    for (int off = 1; off < 64; off <<= 1) {
        int t = __shfl_up(p, off);
        if (lane >= off) p += t;
    }
    if (2 * lane < NBLK_SCAN) btot[2 * lane] = p - b;
    if (2 * lane + 1 < NBLK_SCAN) btot[2 * lane + 1] = p;
}

__launch_bounds__(1024)
__global__ void k_scan3(const int* __restrict__ deg, int* incl_cursor,
                        const int* __restrict__ btot, int* __restrict__ rowptr) {
    const int idx = blockIdx.x * 1024 + threadIdx.x;
    if (idx == 0) rowptr[0] = 0;
    if (idx >= N_NODES) return;
    int off = (blockIdx.x > 0) ? btot[blockIdx.x - 1] : 0;
    int v = incl_cursor[idx] + off;      // inclusive prefix
    rowptr[idx + 1] = v;
    incl_cursor[idx] = v - deg[idx];     // exclusive prefix = fill cursor
}

// XCD-partitioned CSR fill (see k_deg comment). src load only for owned edges.
#define FILL_GRID 2048
__global__ void k_fill(const int* __restrict__ src, const int* __restrict__ dst,
                       int* __restrict__ cursor, int* __restrict__ csr) {
    const int role = blockIdx.x & 7;
    const int nchunk = gridDim.x >> 3;
    const int lo = role * (N_NODES / 8);
    const int hi = lo + (N_NODES / 8);
    for (int e = (blockIdx.x >> 3) * 256 + threadIdx.x; e < N_EDGES;
         e += nchunk * 256) {
        int d = dst[e];
        if (d >= lo && d < hi) {
            int s = src[e];
            int pos = atomicAdd(&cursor[d], 1);
            csr[pos] = s;
        }
    }
}

// x fp32 [N][165] -> xb bf16 [N][168] zero-padded (uint2 = 4 ch per thread)
__global__ void k_cvt(const float* __restrict__ x, uint2* __restrict__ xb2) {
    int idx = blockIdx.x * blockDim.x + threadIdx.x;
    if (idx >= N_NODES * 42) return;
    int n = idx / 42;
    int t = idx - n * 42;
    int c = 4 * t;
    float f0 = x[(size_t)n * IN_C + c];
    float f1 = (c + 1 < IN_C) ? x[(size_t)n * IN_C + c + 1] : 0.f;
    float f2 = (c + 2 < IN_C) ? x[(size_t)n * IN_C + c + 2] : 0.f;
    float f3 = (c + 3 < IN_C) ? x[(size_t)n * IN_C + c + 3] : 0.f;
    uint2 p;
    p.x = pack2bf(f0, f1);
    p.y = pack2bf(f2, f3);
    xb2[idx] = p;
}

// Wt[c][k] = W1l[k][c] (k<165) | W1r[k-168][c] (168<=k<333) | 0, bf16 [256][352]
__global__ void k_wt(const float* __restrict__ W1l, const float* __restrict__ W1r,
                     unsigned short* __restrict__ Wt) {
    int k = blockIdx.x;        // 0..351
    int c = threadIdx.x;       // 0..255
    float v = 0.0f;
    if (k < IN_C) v = W1l[k * HID_C + c];
    else if (k >= XPAD && k < XPAD + IN_C) v = W1r[(k - XPAD) * HID_C + c];
    Wt[(size_t)c * 352 + k] = f2bf(v);
}

// one wave per node: bf16 gather-mean into aggb [N][168].
// Lane owns channels [4*lane, 4*lane+4) (lanes 0..41); one uint2 load per edge,
// unroll-8. At the random-gather L3-service wall (~2.6 TB/s L2-miss, R7).
__global__ void k_agg1b(const int* __restrict__ rowptr, const int* __restrict__ csr,
                        const uint2* __restrict__ xb2, uint2* __restrict__ aggb2) {
    int n = (blockIdx.x * blockDim.x + threadIdx.x) >> 6;
    if (n >= N_NODES) return;
    const int lane = threadIdx.x & 63;
    const bool act = lane < 42;
    int beg = rowptr[n], end = rowptr[n + 1];
    float a0 = 0.f, a1 = 0.f, a2 = 0.f, a3 = 0.f;
    int j = beg;
#define ACC(u) { a0 += bf2f((unsigned short)((u).x & 0xffffu)); \
                 a1 += bf2f((unsigned short)((u).x >> 16)); \
                 a2 += bf2f((unsigned short)((u).y & 0xffffu)); \
                 a3 += bf2f((unsigned short)((u).y >> 16)); }
    for (; j + 7 < end; j += 8) {
        uint2 u[8];
#pragma unroll
        for (int q = 0; q < 8; ++q) {
            int s = csr[j + q];
            u[q] = act ? xb2[(size_t)s * 42 + lane] : make_uint2(0, 0);
        }
#pragma unroll
        for (int q = 0; q < 8; ++q) ACC(u[q]);
    }
    for (; j + 3 < end; j += 4) {
        uint2 u[4];
#pragma unroll
        for (int q = 0; q < 4; ++q) {
            int s = csr[j + q];
            u[q] = act ? xb2[(size_t)s * 42 + lane] : make_uint2(0, 0);
        }
#pragma unroll
        for (int q = 0; q < 4; ++q) ACC(u[q]);
    }
    for (; j < end; ++j) {
        int s0 = csr[j];
        uint2 u0 = act ? xb2[(size_t)s0 * 42 + lane] : make_uint2(0, 0);
        ACC(u0);
    }
#undef ACC
    if (act) {
        float invd = 1.0f / fmaxf((float)(end - beg), 1.0f);
        uint2 p;
        p.x = pack2bf(a0 * invd, a1 * invd);
        p.y = pack2bf(a2 * invd, a3 * invd);
        aggb2[(size_t)n * 42 + lane] = p;
    }
}

// MFMA fused GEMM: h = relu([mean|x] @ [W1l;W1r] + b1) (fp32 in regs);
// yz[n] = {h@W2l, h@W2r} via per-lane partial dot + 16-lane reduce + LDS sum.
// block = 256 thr = 4 waves; GNT=32 nodes x 256 cols; wave w owns cols [64w,64w+64)
__launch_bounds__(256)
__global__ void k_gemm1(const unsigned short* __restrict__ aggb,
                        const unsigned short* __restrict__ xb,
                        const unsigned short* __restrict__ Wt,
                        const float* __restrict__ b1,
                        const float* __restrict__ W2l, const float* __restrict__ W2r,
                        float* __restrict__ yz) {
    __shared__ __align__(16) unsigned short lds[GNT * LDSROW];   // 22.5 KB
    const int tid = threadIdx.x;
    const int lane = tid & 63;
    const int w = tid >> 6;
    const int node0 = blockIdx.x * GNT;

    // stage A tile: row=node, shorts [0,168)=aggb(mean), [168,336)=xb, [336,360)=0
    for (int idx = tid; idx < GNT * 45; idx += 256) {
        int row = idx / 45;
        int c = idx - row * 45;
        int n = node0 + row;
        uint4 v = make_uint4(0, 0, 0, 0);
        if (n < N_NODES) {
            if (c < 21)      v = *(const uint4*)&aggb[(size_t)n * XPAD + c * 8];
            else if (c < 42) v = *(const uint4*)&xb[(size_t)n * XPAD + (c - 21) * 8];
        }
        *(uint4*)&lds[row * LDSROW + c * 8] = v;
    }
    __syncthreads();

    const int arow = lane & 15;       // A row / B col / C col within 16
    const int kgrp = lane >> 4;       // k group
    const int colbase = w * 64;
    f32x4 acc[2][4] = {};

    for (int ks = 0; ks < 11; ++ks) {
        const int k0 = ks * 32 + kgrp * 8;
        bf16x8 bfr[4], afr[2];
#pragma unroll
        for (int n = 0; n < 4; ++n)
            bfr[n] = *(const bf16x8*)&Wt[(size_t)(colbase + n * 16 + arow) * 352 + k0];
#pragma unroll
        for (int m = 0; m < 2; ++m)
            afr[m] = *(const bf16x8*)&lds[(m * 16 + arow) * LDSROW + k0];
#pragma unroll
        for (int m = 0; m < 2; ++m)
#pragma unroll
            for (int n = 0; n < 4; ++n)
                acc[m][n] = __builtin_amdgcn_mfma_f32_16x16x32_bf16(afr[m], bfr[n],
                                                                    acc[m][n], 0, 0, 0);
    }

    // ---- fp32 epilogue: per-lane partial y/z over its 4 cols, reduce 16 lanes ----
    float b1c[4];
    float2 wl[4], wr[4];
#pragma unroll
    for (int n = 0; n < 4; ++n) {
        int c = colbase + n * 16 + arow;
        b1c[n] = b1[c];
        wl[n] = *(const float2*)&W2l[c * 2];
        wr[n] = *(const float2*)&W2r[c * 2];
    }
    __syncthreads();                 // all waves done reading A-tile
    float* part = (float*)lds;       // part[w][row][4] : 4*32*4 floats = 2 KB

#pragma unroll
    for (int m = 0; m < 2; ++m)
#pragma unroll
        for (int r = 0; r < 4; ++r) {
            float y0 = 0.f, y1 = 0.f, z0 = 0.f, z1 = 0.f;
#pragma unroll
            for (int n = 0; n < 4; ++n) {
                float h = fmaxf(acc[m][n][r] + b1c[n], 0.0f);
                y0 = fmaf(h, wl[n].x, y0); y1 = fmaf(h, wl[n].y, y1);
                z0 = fmaf(h, wr[n].x, z0); z1 = fmaf(h, wr[n].y, z1);
            }
#pragma unroll
            for (int off = 1; off < 16; off <<= 1) {
                y0 += __shfl_xor(y0, off); y1 += __shfl_xor(y1, off);
                z0 += __shfl_xor(z0, off); z1 += __shfl_xor(z1, off);
            }
            if (arow == 0) {
                int row = m * 16 + kgrp * 4 + r;
                float* p = &part[(w * GNT + row) * 4];
                p[0] = y0; p[1] = y1; p[2] = z0; p[3] = z1;
            }
        }
    __syncthreads();

    // cross-wave sum: 128 threads = 32 rows x 4 channels
    if (tid < GNT * 4) {
        int row = tid >> 2;
        int ch = tid & 3;
        float s = part[row * 4 + ch] + part[(GNT * 4 + row * 4) + ch] +
                  part[(GNT * 8 + row * 4) + ch] + part[(GNT * 12 + row * 4) + ch];
        int node = node0 + row;
        if (node < N_NODES) yz[(size_t)node * 4 + ch] = s;
    }
}

// one wave per node: out = mean(y[neighbors]) + b2 + z[node]
__global__ void k_layer2(const int* __restrict__ rowptr, const int* __restrict__ csr,
                         const float* __restrict__ yz, const float* __restrict__ b2,
                         float* __restrict__ out) {
    int n = (blockIdx.x * blockDim.x + threadIdx.x) >> 6;
    if (n >= N_NODES) return;
    const int lane = threadIdx.x & 63;
    int beg = rowptr[n], end = rowptr[n + 1];
    float y0 = 0.f, y1 = 0.f;
    for (int i = beg + lane; i < end; i += 64) {
        int s = csr[i];
        float2 v = *(const float2*)&yz[(size_t)s * 4];
        y0 += v.x; y1 += v.y;
    }
#pragma unroll
    for (int off = 32; off >= 1; off >>= 1) {
        y0 += __shfl_xor(y0, off);
        y1 += __shfl_xor(y1, off);
    }
    if (lane == 0) {
        float invd = 1.0f / fmaxf((float)(end - beg), 1.0f);
        float2 o;
        o.x = y0 * invd + b2[0] + yz[(size_t)n * 4 + 2];
        o.y = y1 * invd + b2[1] + yz[(size_t)n * 4 + 3];
        *(float2*)&out[n * 2] = o;
    }
}

extern "C" void kernel_launch(void* const* d_in, const int* in_sizes, int n_in,
                              void* d_out, int out_size, void* d_ws, size_t ws_size,
                              hipStream_t stream) {
    const float* x   = (const float*)d_in[0];
    const int*   ei  = (const int*)d_in[1];
    const int*   src = ei;
    const int*   dst = ei + N_EDGES;
    const float* W1l = (const float*)d_in[2];
    const float* b1  = (const float*)d_in[3];
    const float* W1r = (const float*)d_in[4];
    const float* W2l = (const float*)d_in[5];
    const float* b2  = (const float*)d_in[6];
    const float* W2r = (const float*)d_in[7];
    float* out = (float*)d_out;

    int* wsi = (int*)d_ws;
    int* csr    = wsi;                                   // 1.6M ints
    int* rowptr = wsi + 1600000;                         // 100001 ints
    unsigned short* xb   = (unsigned short*)(wsi + 1700004);
    unsigned short* aggb = xb + (size_t)N_NODES * XPAD;
    unsigned short* Wt   = aggb + (size_t)N_NODES * XPAD;
    float* yz            = (float*)(Wt + 256 * 352);
    // overlays (dead before k_gemm1 writes yz):
    int* deg    = (int*)yz;
    int* inccur = (int*)yz + N_NODES;    // scan1 incl -> scan3 cursor
    int* btot   = (int*)yz + 2 * N_NODES;

    hipMemsetAsync(deg, 0, N_NODES * sizeof(int), stream);

    k_cvt<<<(N_NODES * 42 + 255) / 256, 256, 0, stream>>>(x, (uint2*)xb);
    k_wt<<<352, 256, 0, stream>>>(W1l, W1r, Wt);
    k_deg<<<FILL_GRID, 256, 0, stream>>>(dst, deg);
    k_scan1<<<NBLK_SCAN, 1024, 0, stream>>>(deg, inccur, btot);
    k_scan2<<<1, 64, 0, stream>>>(btot);
    k_scan3<<<NBLK_SCAN, 1024, 0, stream>>>(deg, inccur, btot, rowptr);
    k_fill<<<FILL_GRID, 256, 0, stream>>>(src, dst, inccur, csr);
    k_agg1b<<<(N_NODES * 64 + 255) / 256, 256, 0, stream>>>(rowptr, csr,
                                                            (const uint2*)xb,
                                                            (uint2*)aggb);
    k_gemm1<<<(N_NODES + GNT - 1) / GNT, 256, 0, stream>>>(aggb, xb, Wt, b1,
                                                           W2l, W2r, yz);
    k_layer2<<<(N_NODES * 64 + 255) / 256, 256, 0, stream>>>(rowptr, csr, yz, b2, out);
}